// Round 5
// baseline (241.799 us; speedup 1.0000x reference)
//
#include <hip/hip_runtime.h>
#include <utility>

#define NQ   7
#define DIM  128   // 2^7

// static_for: constant indices in the initial IR -> first SROA scalarizes all
// arrays (R3 proved runtime-indexed st[] lands in scratch: 170 MB writes).
template<class F, int... I>
__device__ __forceinline__ void static_for_impl(F&& f, std::integer_sequence<int, I...>) {
    (f(std::integral_constant<int, I>{}), ...);
}
template<int N, class F>
__device__ __forceinline__ void static_for(F&& f) {
    static_for_impl(static_cast<F&&>(f), std::make_integer_sequence<int, N>{});
}

// One wave per block; each thread ends up with one full 128-float row in
// REGISTERS (static_for) but loads are wave-cooperative COALESCED float4
// (R4's direct 512B-strided loads were L1-thrash-bound: 64 lines/instr,
// 16B used per line). LDS transpose tile: 64 rows x 8 float4 per 32-col
// chunk, row stride 9 float4 (quad spread (r+g)%8), b128 ops throughout.
__global__ __launch_bounds__(64, 2)
void qnat_kernel(const float* __restrict__ embed,
                 const float* __restrict__ theta,
                 float* __restrict__ out)
{
    __shared__ float4 lds4[64 * 9];                     // 9216 B
    const int lane = threadIdx.x;                       // 0..63
    const size_t rowBase = (size_t)blockIdx.x * 64;
    const float4* __restrict__ g4 =
        reinterpret_cast<const float4*>(embed) + rowBase * 32;
    const int gr = lane >> 3;               // row sub-index within an instr
    const int gq = lane & 7;                // float4-col within the chunk

    float st[DIM];
    float4 cur[8];

    // chunk c, instr j: lane loads row (j*8+gr), f4-col (c*8+gq)
    // -> lanes 0..7 are 128B-contiguous: 8 fully-consumed lines / instr.
    static_for<8>([&](auto J) {
        constexpr int j = J.value;
        cur[j] = g4[(size_t)(j * 8 + gr) * 32 + gq];    // chunk 0
    });

    static_for<4>([&](auto C) {
        constexpr int c = C.value;
        float4 nxt[8];
        if constexpr (c < 3) {
            static_for<8>([&](auto J) {                 // prefetch chunk c+1
                constexpr int j = J.value;
                nxt[j] = g4[(size_t)(j * 8 + gr) * 32 + (c + 1) * 8 + gq];
            });
        }
        static_for<8>([&](auto J) {                     // ds_write_b128
            constexpr int j = J.value;
            lds4[(j * 8 + gr) * 9 + gq] = cur[j];
        });
        __syncthreads();                                // 1-wave: cheap
        static_for<8>([&](auto J) {                     // ds_read_b128
            constexpr int j = J.value;
            const float4 v = lds4[lane * 9 + j];
            st[c * 32 + 4 * j + 0] = v.x;
            st[c * 32 + 4 * j + 1] = v.y;
            st[c * 32 + 4 * j + 2] = v.z;
            st[c * 32 + 4 * j + 3] = v.w;
        });
        __syncthreads();
        if constexpr (c < 3) {
            static_for<8>([&](auto J) { cur[J.value] = nxt[J.value]; });
        }
    });

    // ---- squared norm (normalization deferred to the epilogue) ----
    float ss = 0.f;
    static_for<DIM>([&](auto I) {
        constexpr int i = I.value;
        ss = fmaf(st[i], st[i], ss);
    });

    // ---- 2 layers of (7 RY gates + CZ ladder phase) ----
    static_for<2>([&](auto D) {
        constexpr int d = D.value;
        static_for<NQ>([&](auto Q) {
            constexpr int q = Q.value;
            const float half = 0.5f * theta[d * NQ + q];
            const float c_ = __cosf(half);
            const float s_ = __sinf(half);
            static_for<64>([&](auto P) {
                constexpr int p  = P.value;
                constexpr int lo = 1 << q;
                constexpr int i0 = ((p >> q) << (q + 1)) | (p & (lo - 1));
                constexpr int i1 = i0 | lo;
                const float a0 = st[i0], a1 = st[i1];
                st[i0] = fmaf(c_, a0, -s_ * a1);
                st[i1] = fmaf(s_, a0,  c_ * a1);
            });
        });
        static_for<DIM>([&](auto I) {   // CZ: (-1)^popcount(i & i>>1)
            constexpr int i = I.value;
            if constexpr (__builtin_popcount(i & (i >> 1)) & 1) st[i] = -st[i];
        });
    });

    // ---- probs (unnormalized) ----
    static_for<DIM>([&](auto I) {
        constexpr int i = I.value;
        st[i] *= st[i];
    });

    // ---- out[k] = sum_i probs[i]*(1-2*bit_k(i)) : halving sum/diff tree ----
    float o[NQ];
    static_for<NQ>([&](auto K) {
        constexpr int k = K.value;
        constexpr int n = DIM >> (k + 1);
        float acc = 0.f;
        static_for<64>([&](auto I) {
            constexpr int i = I.value;
            if constexpr (i < n) {
                const float a = st[2 * i], b = st[2 * i + 1];
                acc += a - b;
                st[i] = a + b;     // in-place safe: write idx i <= read idx 2i
            }
        });
        o[k] = acc;
    });

    // deferred normalization: probs scale by 1/ss exactly
    const float invss = __builtin_amdgcn_rcpf(ss);
    static_for<NQ>([&](auto K) { o[K.value] *= invss; });

    // ---- repack through LDS (reuse staging buffer) for coalesced stores ----
    float* ldsf = reinterpret_cast<float*>(lds4);
    __syncthreads();
    static_for<NQ>([&](auto K) {
        constexpr int k = K.value;
        ldsf[lane * NQ + k] = o[k];
    });
    __syncthreads();
    float* __restrict__ ob = out + (size_t)blockIdx.x * (64 * NQ);
    static_for<NQ>([&](auto K) {
        constexpr int k = K.value;
        ob[k * 64 + lane] = ldsf[k * 64 + lane];
    });
}

extern "C" void kernel_launch(void* const* d_in, const int* in_sizes, int n_in,
                              void* d_out, int out_size, void* d_ws, size_t ws_size,
                              hipStream_t stream)
{
    const float* embed = (const float*)d_in[0];
    const float* theta = (const float*)d_in[1];
    float* out = (float*)d_out;
    const int batch = in_sizes[0] / DIM;          // 262144
    dim3 grid(batch / 64), block(64);
    hipLaunchKernelGGL(qnat_kernel, grid, block, 0, stream, embed, theta, out);
}

// Round 6
// 193.044 us; speedup vs baseline: 1.2526x; 1.2526x over previous
//
#include <hip/hip_runtime.h>
#include <utility>

#define NQ   7
#define DIM  128
#define HALF 64            // state elements per lane (2 lanes per row)
#define RPB  32            // rows per block (1 wave)

// static_for: constexpr indices in initial IR -> first SROA scalarizes arrays.
template<class F, int... I>
__device__ __forceinline__ void static_for_impl(F&& f, std::integer_sequence<int, I...>) {
    (f(std::integral_constant<int, I>{}), ...);
}
template<int N, class F>
__device__ __forceinline__ void static_for(F&& f) {
    static_for_impl(static_cast<F&&>(f), std::make_integer_sequence<int, N>{});
}

// swap with adjacent lane (2t <-> 2t+1): v_mov_b32 dpp quad_perm:[1,0,3,2]
__device__ __forceinline__ float swap_adj(float x) {
    int v = __builtin_amdgcn_update_dpp(0, __builtin_bit_cast(int, x),
                                        0xB1 /*quad_perm [1,0,3,2]*/,
                                        0xF, 0xF, true);
    return __builtin_bit_cast(float, v);
}

// 2 lanes per row: lane 2t+h owns elements [h*64, h*64+64) of row t.
// Peak VGPR pressure ~95: the 16 staged float4 loads die into LDS before
// st[64] fills (R5 lesson: st[128]+staging temps > 256 regs -> scratch).
__global__ __launch_bounds__(64, 2)
void qnat_kernel(const float* __restrict__ embed,
                 const float* __restrict__ theta,
                 float* __restrict__ out)
{
    __shared__ float4 tile[RPB * 33];                  // 16896 B, pad=1 float4
    const int lane = threadIdx.x;                      // 0..63
    const int t = lane >> 1;                           // row within block
    const int h = lane & 1;                            // half of the row
    const float4* __restrict__ g4 =
        reinterpret_cast<const float4*>(embed) + (size_t)blockIdx.x * (RPB * 32);

    // ---- coalesced stage-in: 16 x 1KB instructions, full lines ----
    static_for<16>([&](auto J) {
        constexpr int j = J.value;
        const float4 v = g4[j * 64 + lane];
        tile[(2 * j + (lane >> 5)) * 33 + (lane & 31)] = v;
    });
    __syncthreads();

    float st[HALF];
    static_for<16>([&](auto J) {                       // ds_read_b128 x16
        constexpr int j = J.value;
        const float4 v = tile[t * 33 + h * 16 + j];
        st[4 * j + 0] = v.x;
        st[4 * j + 1] = v.y;
        st[4 * j + 2] = v.z;
        st[4 * j + 3] = v.w;
    });

    // ---- squared norm of full row (normalization deferred) ----
    float ss = 0.f;
    static_for<HALF>([&](auto I) {
        constexpr int i = I.value;
        ss = fmaf(st[i], st[i], ss);
    });
    ss += swap_adj(ss);

    const float hs = h ? -1.f : 1.f;

    // ---- 2 layers of (7 RY gates + CZ ladder) ----
    static_for<2>([&](auto D) {
        constexpr int d = D.value;
        // q = 0..5: pairs stay within the lane's half
        static_for<6>([&](auto Q) {
            constexpr int q = Q.value;
            const float ha = 0.5f * theta[d * NQ + q];
            const float c_ = __cosf(ha), s_ = __sinf(ha);
            static_for<32>([&](auto P) {
                constexpr int p  = P.value;
                constexpr int lo = 1 << q;
                constexpr int i0 = ((p >> q) << (q + 1)) | (p & (lo - 1));
                constexpr int i1 = i0 | lo;
                const float a0 = st[i0], a1 = st[i1];
                st[i0] = fmaf(c_, a0, -s_ * a1);
                st[i1] = fmaf(s_, a0,  c_ * a1);
            });
        });
        // q = 6: partner lane holds the other half-row
        {
            const float ha = 0.5f * theta[d * NQ + 6];
            const float c_ = __cosf(ha), s_ = __sinf(ha);
            const float sgn = h ? s_ : -s_;   // h=0: c*a0 - s*a1 ; h=1: s*a0 + c*a1
            static_for<HALF>([&](auto J) {
                constexpr int j = J.value;
                const float other = swap_adj(st[j]);
                st[j] = fmaf(sgn, other, c_ * st[j]);
            });
        }
        // CZ: global g = h*64+j; parity = popcount(j&(j>>1)) ^ (bit5(j)&h)
        static_for<HALF>([&](auto J) {
            constexpr int j = J.value;
            if constexpr ((__builtin_popcount(j & (j >> 1)) & 1) == 1) st[j] = -st[j];
            if constexpr (((j >> 5) & 1) == 1) st[j] *= hs;   // bit5*bit6 term
        });
    });

    // ---- probs (unnormalized) ----
    static_for<HALF>([&](auto J) {
        constexpr int j = J.value;
        st[j] *= st[j];
    });

    // ---- Walsh: local halving tree (k=0..5), cross-lane combine ----
    float o[NQ];
    static_for<6>([&](auto K) {
        constexpr int k = K.value;
        constexpr int n = HALF >> (k + 1);
        float acc = 0.f;
        static_for<32>([&](auto I) {
            constexpr int i = I.value;
            if constexpr (i < n) {
                const float a = st[2 * i], b = st[2 * i + 1];
                acc += a - b;
                st[i] = a + b;       // write idx i <= read idx 2i: safe
            }
        });
        o[k] = acc;
    });
    static_for<6>([&](auto K) {
        constexpr int k = K.value;
        o[k] += swap_adj(o[k]);                 // sum both halves
    });
    {
        const float part = st[0];               // sum of local probs
        o[6] = hs * (part - swap_adj(part));    // = part(h=0) - part(h=1)
    }
    const float invss = __builtin_amdgcn_rcpf(ss);
    static_for<NQ>([&](auto K) { o[K.value] *= invss; });

    // ---- repack through LDS for coalesced stores (224 floats/block) ----
    __syncthreads();
    float* ldsf = reinterpret_cast<float*>(tile);
    if (h == 0) {
        static_for<NQ>([&](auto K) {
            constexpr int k = K.value;
            ldsf[t * NQ + k] = o[k];
        });
    }
    __syncthreads();
    float* __restrict__ ob = out + (size_t)blockIdx.x * (RPB * NQ);
    static_for<4>([&](auto It) {
        constexpr int it = It.value;
        const int idx = it * 64 + lane;
        if constexpr (it < 3) {
            ob[idx] = ldsf[idx];
        } else {
            if (idx < RPB * NQ) ob[idx] = ldsf[idx];
        }
    });
}

extern "C" void kernel_launch(void* const* d_in, const int* in_sizes, int n_in,
                              void* d_out, int out_size, void* d_ws, size_t ws_size,
                              hipStream_t stream)
{
    const float* embed = (const float*)d_in[0];
    const float* theta = (const float*)d_in[1];
    float* out = (float*)d_out;
    const int batch = in_sizes[0] / DIM;          // 262144
    dim3 grid(batch / RPB), block(64);
    hipLaunchKernelGGL(qnat_kernel, grid, block, 0, stream, embed, theta, out);
}